// Round 12
// baseline (119.865 us; speedup 1.0000x reference)
//
#include <hip/hip_runtime.h>

#define T      64
#define S      32
#define NGRAPH 64
#define NW     4

// Fully-fused delta-encoded ECT: ONE dispatch, one block per graph.
// Per (node,theta) the sigmoid profile over s is 0..0, sm, s0, ~1..1; its
// first difference has 3 nonzero deltas at slots ss-1, ss, ss+1 (third
// ~ 1-s0v, err <= 8.2e-4; R9/R10-validated, absmax 4.0). Slots <= 0 fold
// into a base register (profile value at s=0); slots >= 32 -> trash bin 33.
// Per-thread LDS bins, reads-then-writes RMW (no atomics of any scope).
// In-block prefix over s, then plain coalesced stores straight to out
// (all 2048 cells per graph written -> no memset, no ws, no reduce).
__global__ __launch_bounds__(256, 2) void ect_fused(
    const float* __restrict__ x, const float* __restrict__ v,
    const float* __restrict__ lin, const int* __restrict__ batch,
    float* __restrict__ out, int n_points)
{
    __shared__ float bins[256 * 34];  // [tid][c]: 0=base, 1..31 deltas, 33 trash

    const int tid = threadIdx.x;
    const int t   = tid & 63;         // lane == theta
    const int w   = tid >> 6;         // wave id
    const int g   = blockIdx.x;       // graph

    // vectorized zero-init: 8704 floats = 2176 float4
    {
        const float4 z4 = {0.0f, 0.0f, 0.0f, 0.0f};
        float4* b4 = (float4*)bins;
        for (int i = tid; i < 256 * 34 / 4; i += 256) b4[i] = z4;
    }

    // 32-ary ballot search (lanes<32: lower_bound(g), >=32: lower_bound(g+1))
    // rounds shrink range 65536 -> 2048 -> 64 -> 2; ONE final check resolves.
    const int target = (t < 32) ? g : (g + 1);
    const int i32    = t & 31;
    int lo = 0;
    const int strides[3] = {2048, 64, 2};
#pragma unroll
    for (int rnd = 0; rnd < 3; rnd++) {
        const int stride = strides[rnd];
        const int idx  = lo + i32 * stride;
        const int pv   = batch[min(idx, n_points - 1)];
        const bool prd = (idx < n_points) && (pv < target);
        const unsigned long long bal = __ballot(prd);
        const int cnt = __popc((unsigned)(bal >> (t & 32)));
        lo += max(cnt - 1, 0) * stride;
    }
    if ((lo < n_points) && (batch[min(lo, n_points - 1)] < target)) lo++;
    const int n0 = __builtin_amdgcn_readfirstlane(lo);   // lower_bound(g)
    const int n1 = __builtin_amdgcn_readlane(lo, 32);    // lower_bound(g+1)

    const float lin0     = lin[0];
    const float step     = lin[1] - lin0;
    const float inv_step = 1.0f / step;
    const float nl0i     = -lin0 * inv_step;
    const float K2 = (100.0f * step) * 1.4426950408889634f;   // ~10.24
    const float r  = __builtin_amdgcn_exp2f(-K2);

    const float v0 = v[0 * T + t];
    const float v1 = v[1 * T + t];
    const float v2 = v[2 * T + t];

    float v0acc = 0.0f;                 // profile value at s=0
    const int binb = tid * 34;
    __syncthreads();

#pragma unroll 2
    for (int n = n0 + w; n < n1; n += NW) {     // n wave-uniform -> s_loads
        const float x0 = x[3 * n + 0];
        const float x1 = x[3 * n + 1];
        const float x2 = x[3 * n + 2];
        const float nh = fmaf(x0, v0, fmaf(x1, v1, x2 * v2));
        const float f  = fmaf(nh, inv_step, nl0i);
        const float fs = ceilf(f);
        const int   ss = (int)fs;
        const float e0 = __builtin_amdgcn_exp2f(fmaf(K2, f - fs, K2)); // (1,e^d]
        const float e1 = e0 * r;                                        // (r,1]
        const float sm  = __builtin_amdgcn_rcpf(1.0f + e0);
        const float s0v = __builtin_amdgcn_rcpf(1.0f + e1);
        v0acc += (ss <= -1) ? 1.0f : (ss == 0 ? s0v : (ss == 1 ? sm : 0.0f));
        // deltas at slots ss-1, ss, ss+1; in-range [1,31] else trash (33)
        const int p0 = ss - 1, p1 = ss, p2 = ss + 1;
        const int a0 = binb + (((unsigned)(p0 - 1) < 31u) ? p0 : 33);
        const int a1 = binb + (((unsigned)(p1 - 1) < 31u) ? p1 : 33);
        const int a2 = binb + (((unsigned)(p2 - 1) < 31u) ? p2 : 33);
        // reads first, then writes (in-range addrs distinct; trash dontcare)
        const float r0 = bins[a0], r1 = bins[a1], r2 = bins[a2];
        bins[a0] = r0 + sm;
        bins[a1] = r1 + (s0v - sm);
        bins[a2] = r2 + (1.0f - s0v);
    }

    bins[binb + 0] = v0acc;
    __syncthreads();

    // merge 4 wave-banks into bank 0 (c = 0..31; trash column skipped)
    for (int cell = tid; cell < 32 * 64; cell += 256) {
        const int cc = cell >> 6;               // 0..31
        const int tt = cell & 63;
        const float sum = bins[(  0 + tt) * 34 + cc] + bins[( 64 + tt) * 34 + cc]
                        + bins[(128 + tt) * 34 + cc] + bins[(192 + tt) * 34 + cc];
        bins[tt * 34 + cc] = sum;
    }
    __syncthreads();

    // prefix over c and coalesced store DIRECT to out: wave w -> s in [8w,8w+8)
    float run = bins[t * 34 + 0];               // base = value at s=0
    const int sbase = 8 * w;
    for (int cc = 1; cc < sbase; cc++) run += bins[t * 34 + cc];
    float* og = out + g * (S * T);
#pragma unroll
    for (int j = 0; j < 8; j++) {
        const int s = sbase + j;
        if (s >= 1) run += bins[t * 34 + s];
        og[s * T + t] = run;                    // covers every cell: no memset
    }
}

extern "C" void kernel_launch(void* const* d_in, const int* in_sizes, int n_in,
                              void* d_out, int out_size, void* d_ws, size_t ws_size,
                              hipStream_t stream) {
    const float* x     = (const float*)d_in[0];
    const float* v     = (const float*)d_in[1];
    const float* lin   = (const float*)d_in[2];
    const int*   batch = (const int*)d_in[3];
    float* out = (float*)d_out;

    const int n_points = in_sizes[0] / 3;

    ect_fused<<<NGRAPH, 256, 0, stream>>>(x, v, lin, batch, out, n_points);
}

// Round 13
// 73.609 us; speedup vs baseline: 1.6284x; 1.6284x over previous
//
#include <hip/hip_runtime.h>

#define T      64
#define S      32
#define NGRAPH 64
#define NSPLIT 8      // slices per graph -> 512 blocks of 256 (2 blocks/CU)
#define NW     4

// Delta-encoded ECT with TRANSPOSED bins: bins[c*256 + tid] so the LDS bank
// (= tid mod 32) is independent of the data-dependent slot c. R12 exposed
// 2M bank-conflict cycles (~20 cyc/LDS op) with the old [tid][c] layout;
// this layout is conflict-free by construction (2 lanes/bank = free).
// Numerics (R9/R10-validated, absmax 4.0): per (node,theta) profile is
// 0..0, sm, s0, ~1..1; 3 deltas at slots ss-1, ss, ss+1 (third ~ 1-s0v,
// err <= 8.2e-4); slots <= 0 fold into base register; slots >= 32 -> trash.
__global__ __launch_bounds__(256, 2) void ect_partial(
    const float* __restrict__ x, const float* __restrict__ v,
    const float* __restrict__ lin, const int* __restrict__ batch,
    float* __restrict__ ws, int n_points)
{
    __shared__ float bins[34 * 256]; // [c][tid]: c=0 base, 1..31 deltas, 33 trash

    const int tid  = threadIdx.x;
    const int t    = tid & 63;       // lane == theta
    const int w    = tid >> 6;       // wave id
    const int b    = blockIdx.x;
    const int g    = b >> 3;         // graph
    const int c    = b & (NSPLIT - 1);

    {   // vectorized zero-init: 8704 floats = 2176 float4
        const float4 z4 = {0.0f, 0.0f, 0.0f, 0.0f};
        float4* b4 = (float4*)bins;
        for (int i = tid; i < 34 * 256 / 4; i += 256) b4[i] = z4;
    }

    // 32-ary ballot search (lanes<32: lower_bound(g), >=32: lower_bound(g+1))
    const int target = (t < 32) ? g : (g + 1);
    const int i32    = t & 31;
    int lo = 0;
    const int strides[3] = {2048, 64, 2};
#pragma unroll
    for (int rnd = 0; rnd < 3; rnd++) {
        const int stride = strides[rnd];
        const int idx  = lo + i32 * stride;
        const int pv   = batch[min(idx, n_points - 1)];
        const bool prd = (idx < n_points) && (pv < target);
        const unsigned long long bal = __ballot(prd);
        const int cnt = __popc((unsigned)(bal >> (t & 32)));
        lo += max(cnt - 1, 0) * stride;
    }
    if ((lo < n_points) && (batch[min(lo, n_points - 1)] < target)) lo++;
    const int gstart = __builtin_amdgcn_readfirstlane(lo);
    const int gend   = __builtin_amdgcn_readlane(lo, 32);
    const int len    = gend - gstart;
    const int n0     = gstart + (len * c) / NSPLIT;
    const int n1     = gstart + (len * (c + 1)) / NSPLIT;

    const float lin0     = lin[0];
    const float step     = lin[1] - lin0;
    const float inv_step = 1.0f / step;
    const float nl0i     = -lin0 * inv_step;
    const float K2 = (100.0f * step) * 1.4426950408889634f;   // ~10.24
    const float r  = __builtin_amdgcn_exp2f(-K2);

    const float v0 = v[0 * T + t];
    const float v1 = v[1 * T + t];
    const float v2 = v[2 * T + t];

    float v0acc = 0.0f;                 // profile value at s=0
    __syncthreads();

#pragma unroll 2
    for (int n = n0 + w; n < n1; n += NW) {     // n wave-uniform -> s_loads
        const float x0 = x[3 * n + 0];
        const float x1 = x[3 * n + 1];
        const float x2 = x[3 * n + 2];
        const float nh = fmaf(x0, v0, fmaf(x1, v1, x2 * v2));
        const float f  = fmaf(nh, inv_step, nl0i);
        const float fs = ceilf(f);
        const int   ss = (int)fs;
        const float e0 = __builtin_amdgcn_exp2f(fmaf(K2, f - fs, K2)); // (1,e^d]
        const float e1 = e0 * r;                                        // (r,1]
        const float sm  = __builtin_amdgcn_rcpf(1.0f + e0);
        const float s0v = __builtin_amdgcn_rcpf(1.0f + e1);
        v0acc += (ss <= -1) ? 1.0f : (ss == 0 ? s0v : (ss == 1 ? sm : 0.0f));
        // deltas at slots ss-1, ss, ss+1; in-range [1,31] else trash (33)
        const int p0 = ss - 1, p1 = ss, p2 = ss + 1;
        const int a0 = (((unsigned)(p0 - 1) < 31u) ? p0 : 33) * 256 + tid;
        const int a1 = (((unsigned)(p1 - 1) < 31u) ? p1 : 33) * 256 + tid;
        const int a2 = (((unsigned)(p2 - 1) < 31u) ? p2 : 33) * 256 + tid;
        // reads first, then writes (in-range addrs distinct; trash dontcare);
        // bank = tid mod 32 for all -> conflict-free
        const float r0 = bins[a0], r1 = bins[a1], r2 = bins[a2];
        bins[a0] = r0 + sm;
        bins[a1] = r1 + (s0v - sm);
        bins[a2] = r2 + (1.0f - s0v);
    }

    bins[0 * 256 + tid] = v0acc;
    __syncthreads();

    // merge 4 wave-lanes into tid = t (c = 0..31; trash skipped)
    for (int cell = tid; cell < 32 * 64; cell += 256) {
        const int cc = cell >> 6;               // 0..31
        const int tt = cell & 63;
        const float sum = bins[cc * 256 +   0 + tt] + bins[cc * 256 +  64 + tt]
                        + bins[cc * 256 + 128 + tt] + bins[cc * 256 + 192 + tt];
        bins[cc * 256 + tt] = sum;              // same-thread RMW, safe
    }
    __syncthreads();

    // prefix over c and coalesced store: wave w covers s in [8w, 8w+8)
    float run = bins[0 * 256 + t];              // base = value at s=0
    const int sbase = 8 * w;
    for (int cc = 1; cc < sbase; cc++) run += bins[cc * 256 + t];
    float* wsb = ws + (size_t)b * (S * T);
#pragma unroll
    for (int j = 0; j < 8; j++) {
        const int s = sbase + j;
        if (s >= 1) run += bins[s * 256 + t];
        wsb[s * T + t] = run;
    }
}

// Phase 2: out[g][i] = sum of 8 prefixed slice partials, float4-wide
// (plain stores cover the whole output -> no memset needed)
__global__ __launch_bounds__(256) void ect_reduce(
    const float4* __restrict__ ws4, float4* __restrict__ out4)
{
    const int idx = blockIdx.x * 256 + threadIdx.x;  // [0, 64*512)
    const int g   = idx >> 9;                        // 512 float4 per graph
    const int i   = idx & 511;
    float4 sum = {0.0f, 0.0f, 0.0f, 0.0f};
#pragma unroll
    for (int c = 0; c < NSPLIT; c++) {
        const float4 a = ws4[(size_t)(g * NSPLIT + c) * 512 + i];
        sum.x += a.x; sum.y += a.y; sum.z += a.z; sum.w += a.w;
    }
    out4[idx] = sum;
}

extern "C" void kernel_launch(void* const* d_in, const int* in_sizes, int n_in,
                              void* d_out, int out_size, void* d_ws, size_t ws_size,
                              hipStream_t stream) {
    const float* x     = (const float*)d_in[0];
    const float* v     = (const float*)d_in[1];
    const float* lin   = (const float*)d_in[2];
    const int*   batch = (const int*)d_in[3];
    float* out = (float*)d_out;
    float* ws  = (float*)d_ws;                   // 512 * 2048 floats = 4.2 MB

    const int n_points = in_sizes[0] / 3;

    ect_partial<<<NGRAPH * NSPLIT, 256, 0, stream>>>(x, v, lin, batch, ws, n_points);
    ect_reduce<<<NGRAPH * S * T / 4 / 256, 256, 0, stream>>>(
        (const float4*)ws, (float4*)out);
}